// Round 5
// baseline (794.759 us; speedup 1.0000x reference)
//
#include <hip/hip_runtime.h>

#define NN 100000
#define NE 3200000
#define FD 128
#define NBUK 782                 // ceil(NN/128), rows per bucket = 128
#define NSEG (NBUK * 8)          // 6256 (bucket-major, group-minor)
#define NBIN 1024                // binning blocks; NE % NBIN == 0
#define CHUNK (NE / NBIN)        // 3125 edges per binning block
#define MAXB 5120                // LDS stage capacity per bucket (λ=4096, 16σ margin)

// ---------------- bf16 helpers (manual, RNE) ----------------
__device__ inline unsigned int f2bf_bits(float x) {
    unsigned int u = __float_as_uint(x);
    return (u + 0x7fffu + ((u >> 16) & 1u)) >> 16;
}
__device__ inline float bf_lo(unsigned int u) { return __uint_as_float(u << 16); }
__device__ inline float bf_hi(unsigned int u) { return __uint_as_float(u & 0xffff0000u); }

// ---------------------------------------------------------------------------
// Fused triple GEMM:  OUT = X@H0 (f32), V = X@H1 (f32), T2 = X@H2 (bf16)
// 512 threads, 128-row tile, 4 rows/thread -> 2 blocks/CU = 4 waves/SIMD.
// H streamed from L1/L2 (shared by all blocks); X tile in LDS.
// ---------------------------------------------------------------------------
__global__ __launch_bounds__(512, 4)
void gemm3_kernel(const float* __restrict__ X, const float* __restrict__ H,
                  float* __restrict__ OUT, float* __restrict__ V,
                  unsigned short* __restrict__ T2bf) {
    __shared__ float Xs[128][132];
    const int tid  = threadIdx.x;
    const int row0 = blockIdx.x * 128;

    #pragma unroll
    for (int it = 0; it < 8; ++it) {
        int idx = (it * 512 + tid) * 4;
        int r = idx >> 7, c = idx & 127;
        int gr = row0 + r;
        float4 v = make_float4(0.f, 0.f, 0.f, 0.f);
        if (gr < NN) v = *reinterpret_cast<const float4*>(X + gr * FD + c);
        *reinterpret_cast<float4*>(&Xs[r][c]) = v;
    }
    __syncthreads();

    const int tx = tid & 15;     // col group: cols tx*4..+3 and 64+tx*4..+3
    const int ty = tid >> 4;     // row group: rows ty + 32*i, i<4

    #pragma unroll
    for (int k = 0; k < 3; ++k) {
        const float* Hk = H + k * (FD * FD);
        float acc[4][8];
        #pragma unroll
        for (int i = 0; i < 4; ++i)
            #pragma unroll
            for (int j = 0; j < 8; ++j) acc[i][j] = 0.f;

        #pragma unroll 2
        for (int kk = 0; kk < FD; kk += 4) {
            float4 xq[4];
            #pragma unroll
            for (int i = 0; i < 4; ++i)
                xq[i] = *reinterpret_cast<const float4*>(&Xs[ty + 32 * i][kk]);
            #pragma unroll
            for (int s = 0; s < 4; ++s) {
                float4 h0 = *reinterpret_cast<const float4*>(Hk + (kk + s) * FD + tx * 4);
                float4 h1 = *reinterpret_cast<const float4*>(Hk + (kk + s) * FD + 64 + tx * 4);
                #pragma unroll
                for (int i = 0; i < 4; ++i) {
                    float xv = (s == 0) ? xq[i].x : (s == 1) ? xq[i].y
                             : (s == 2) ? xq[i].z : xq[i].w;
                    acc[i][0] += xv * h0.x; acc[i][1] += xv * h0.y;
                    acc[i][2] += xv * h0.z; acc[i][3] += xv * h0.w;
                    acc[i][4] += xv * h1.x; acc[i][5] += xv * h1.y;
                    acc[i][6] += xv * h1.z; acc[i][7] += xv * h1.w;
                }
            }
        }

        if (k < 2) {
            float* dst = k ? V : OUT;
            #pragma unroll
            for (int i = 0; i < 4; ++i) {
                int gr = row0 + ty + 32 * i;
                if (gr < NN) {
                    float4 a = make_float4(acc[i][0], acc[i][1], acc[i][2], acc[i][3]);
                    float4 b = make_float4(acc[i][4], acc[i][5], acc[i][6], acc[i][7]);
                    *reinterpret_cast<float4*>(dst + (size_t)gr * FD + tx * 4)      = a;
                    *reinterpret_cast<float4*>(dst + (size_t)gr * FD + 64 + tx * 4) = b;
                }
            }
        } else {
            #pragma unroll
            for (int i = 0; i < 4; ++i) {
                int gr = row0 + ty + 32 * i;
                if (gr < NN) {
                    unsigned int w0 = f2bf_bits(acc[i][0]) | (f2bf_bits(acc[i][1]) << 16);
                    unsigned int w1 = f2bf_bits(acc[i][2]) | (f2bf_bits(acc[i][3]) << 16);
                    unsigned int w2 = f2bf_bits(acc[i][4]) | (f2bf_bits(acc[i][5]) << 16);
                    unsigned int w3 = f2bf_bits(acc[i][6]) | (f2bf_bits(acc[i][7]) << 16);
                    *reinterpret_cast<uint2*>(T2bf + (size_t)gr * FD + tx * 4)      = make_uint2(w0, w1);
                    *reinterpret_cast<uint2*>(T2bf + (size_t)gr * FD + 64 + tx * 4) = make_uint2(w2, w3);
                }
            }
        }
    }
}

// ---------------------------------------------------------------------------
// Bucketed CSR build (unchanged from round 4).
// ---------------------------------------------------------------------------
__global__ __launch_bounds__(256)
void zero_counts(int* __restrict__ counts) {
    int i = blockIdx.x * 256 + threadIdx.x;
    if (i < NSEG) counts[i] = 0;
}

__global__ __launch_bounds__(256)
void bucket_hist(const int* __restrict__ rows, int* __restrict__ counts) {
    __shared__ int lh[NBUK];
    for (int i = threadIdx.x; i < NBUK; i += 256) lh[i] = 0;
    __syncthreads();
    const int beg = blockIdx.x * CHUNK, end = beg + CHUNK;
    for (int e = beg + threadIdx.x; e < end; e += 256)
        atomicAdd(&lh[rows[e] >> 7], 1);
    __syncthreads();
    const int g = blockIdx.x & 7;
    for (int b = threadIdx.x; b < NBUK; b += 256)
        if (lh[b]) atomicAdd(&counts[b * 8 + g], lh[b]);
}

__global__ __launch_bounds__(1024)
void scan_segs(const int* __restrict__ counts, int* __restrict__ cursor,
               int* __restrict__ bucket_ptr) {
    __shared__ int s[1024];
    const int tid = threadIdx.x;
    const int per = (NSEG + 1023) / 1024;   // 7
    const int base = tid * per;
    int sum = 0;
    for (int i = 0; i < per; ++i) {
        int idx = base + i;
        if (idx < NSEG) sum += counts[idx];
    }
    s[tid] = sum;
    __syncthreads();
    for (int off = 1; off < 1024; off <<= 1) {
        int t = (tid >= off) ? s[tid - off] : 0;
        __syncthreads();
        s[tid] += t;
        __syncthreads();
    }
    int run = s[tid] - sum;                  // exclusive
    for (int i = 0; i < per; ++i) {
        int idx = base + i;
        if (idx < NSEG) {
            cursor[idx] = run;
            if ((idx & 7) == 0) bucket_ptr[idx >> 3] = run;
            run += counts[idx];
        }
    }
    if (tid == 1023) bucket_ptr[NBUK] = NE;
}

// records: x = (rowlow7 << 17) | col17 ; y = val bits
__global__ __launch_bounds__(256)
void bin_scatter(const int* __restrict__ rows, const int* __restrict__ cols,
                 const float* __restrict__ vals, int* __restrict__ cursor,
                 uint2* __restrict__ recs) {
    const int beg = blockIdx.x * CHUNK, end = beg + CHUNK;
    const int g = blockIdx.x & 7;
    for (int e = beg + threadIdx.x; e < end; e += 256) {
        int r = rows[e];
        int b = r >> 7;
        int pos = atomicAdd(&cursor[b * 8 + g], 1);
        recs[pos] = make_uint2(((unsigned)(r & 127) << 17) | (unsigned)cols[e],
                               __float_as_uint(vals[e]));
    }
}

__global__ __launch_bounds__(256)
void bucket_csr(uint2* __restrict__ recs, const int* __restrict__ bucket_ptr,
                int* __restrict__ row_ptr) {
    __shared__ uint2 stage[MAXB];
    __shared__ int lh[128];
    __shared__ int lsc[128];
    const int b = blockIdx.x, tid = threadIdx.x;
    const int beg = bucket_ptr[b], end = bucket_ptr[b + 1];
    const int n = end - beg;

    if (tid < 128) lh[tid] = 0;
    __syncthreads();
    for (int i = tid; i < n; i += 256) {
        uint2 r = recs[beg + i];
        stage[i] = r;
        atomicAdd(&lh[r.x >> 17], 1);
    }
    __syncthreads();
    int v = (tid < 128) ? lh[tid] : 0;
    if (tid < 128) lsc[tid] = v;
    __syncthreads();
    for (int off = 1; off < 128; off <<= 1) {
        int t = 0;
        if (tid < 128 && tid >= off) t = lsc[tid - off];
        __syncthreads();
        if (tid < 128) lsc[tid] += t;
        __syncthreads();
    }
    if (tid < 128) {
        int excl = lsc[tid] - v;
        int gr = b * 128 + tid;
        if (gr <= NN) row_ptr[gr] = beg + excl;
        lh[tid] = excl;                            // reuse as local cursor
    }
    __syncthreads();
    for (int i = tid; i < n; i += 256) {
        uint2 r = stage[i];
        int pos = atomicAdd(&lh[r.x >> 17], 1);
        recs[beg + pos] = r;
    }
}

// ---------------------------------------------------------------------------
// SpMM (CSR, bf16 gathers, fp32 accumulate). One wave per dest row.
// lane = (edge-parity l>>5, feature-quad l&31): each uint2 gather instruction
// moves 512B (two src rows) -> 2x bytes-in-flight vs one-row-per-wave.
// Halves combined at the end with __shfl_xor(32); lanes<32 store.
// ---------------------------------------------------------------------------
#define SPMM_BODY(ACC_INIT, STORE)                                             \
    const int lane = threadIdx.x & 63;                                         \
    const int row  = (blockIdx.x * blockDim.x + threadIdx.x) >> 6;             \
    if (row >= NN) return;                                                     \
    const int sub = lane >> 5;      /* which edge of the pair */               \
    const int fq  = lane & 31;      /* feature quad: fq*4..fq*4+3 */           \
    const int beg = row_ptr[row], end = row_ptr[row + 1];                      \
    float4 acc = make_float4(0.f, 0.f, 0.f, 0.f);                              \
    int e = beg + sub;                                                         \
    for (; e + 14 < end; e += 16) {                                            \
        uint2 p[8];                                                            \
        uint2 g[8];                                                            \
        _Pragma("unroll")                                                      \
        for (int u = 0; u < 8; ++u) p[u] = recs[e + 2 * u];                    \
        _Pragma("unroll")                                                      \
        for (int u = 0; u < 8; ++u)                                            \
            g[u] = *reinterpret_cast<const uint2*>(                            \
                src + (size_t)(p[u].x & 0x1FFFF) * FD + fq * 4);               \
        _Pragma("unroll")                                                      \
        for (int u = 0; u < 8; ++u) {                                          \
            float v = __uint_as_float(p[u].y);                                 \
            acc.x += v * bf_lo(g[u].x); acc.y += v * bf_hi(g[u].x);            \
            acc.z += v * bf_lo(g[u].y); acc.w += v * bf_hi(g[u].y);            \
        }                                                                      \
    }                                                                          \
    for (; e < end; e += 2) {                                                  \
        uint2 p = recs[e];                                                     \
        uint2 g = *reinterpret_cast<const uint2*>(                             \
            src + (size_t)(p.x & 0x1FFFF) * FD + fq * 4);                      \
        float v = __uint_as_float(p.y);                                        \
        acc.x += v * bf_lo(g.x); acc.y += v * bf_hi(g.x);                      \
        acc.z += v * bf_lo(g.y); acc.w += v * bf_hi(g.y);                      \
    }                                                                          \
    acc.x += __shfl_xor(acc.x, 32, 64);                                        \
    acc.y += __shfl_xor(acc.y, 32, 64);                                        \
    acc.z += __shfl_xor(acc.z, 32, 64);                                        \
    acc.w += __shfl_xor(acc.w, 32, 64);                                        \
    if (sub == 0) { STORE }

__global__ __launch_bounds__(256)
void spmm_bf_bf(const int* __restrict__ row_ptr, const uint2* __restrict__ recs,
                const unsigned short* __restrict__ src,
                const float* __restrict__ init, unsigned short* __restrict__ dst) {
    SPMM_BODY(
        ;,
        {
            float4 iv = *reinterpret_cast<const float4*>(init + (size_t)row * FD + fq * 4);
            acc.x += iv.x; acc.y += iv.y; acc.z += iv.z; acc.w += iv.w;
            unsigned int w0 = f2bf_bits(acc.x) | (f2bf_bits(acc.y) << 16);
            unsigned int w1 = f2bf_bits(acc.z) | (f2bf_bits(acc.w) << 16);
            *reinterpret_cast<uint2*>(dst + (size_t)row * FD + fq * 4) = make_uint2(w0, w1);
        })
}

__global__ __launch_bounds__(256)
void spmm_bf_f32(const int* __restrict__ row_ptr, const uint2* __restrict__ recs,
                 const unsigned short* __restrict__ src, float* __restrict__ dst) {
    SPMM_BODY(
        ;,
        {
            float4 iv = *reinterpret_cast<const float4*>(dst + (size_t)row * FD + fq * 4);
            acc.x += iv.x; acc.y += iv.y; acc.z += iv.z; acc.w += iv.w;
            *reinterpret_cast<float4*>(dst + (size_t)row * FD + fq * 4) = acc;
        })
}

extern "C" void kernel_launch(void* const* d_in, const int* in_sizes, int n_in,
                              void* d_out, int out_size, void* d_ws, size_t ws_size,
                              hipStream_t stream) {
    const int*   edge_rows = (const int*)d_in[0];
    const int*   edge_cols = (const int*)d_in[1];
    const float* edge_vals = (const float*)d_in[2];
    const float* x         = (const float*)d_in[3];
    const float* H         = (const float*)d_in[4];
    float*       out       = (float*)d_out;

    // workspace layout (~128.5 MB total)
    const size_t feat = (size_t)NN * FD;
    float*          V_f32 = (float*)d_ws;                      // 51.2 MB
    unsigned short* T2bf  = (unsigned short*)(V_f32 + feat);   // 25.6 MB
    unsigned short* Vbf   = T2bf + feat;                       // 25.6 MB
    uint2*          recs  = (uint2*)(Vbf + feat);              // 25.6 MB
    int* counts     = (int*)(recs + NE);                       // 25 KB
    int* cursor     = counts + NSEG;                           // 25 KB
    int* row_ptr    = cursor + NSEG;                           // 400 KB
    int* bucket_ptr = row_ptr + NN + 1;                        // 3.1 KB

    // OUT = X@H0, V_f32 = X@H1, T2bf = bf16(X@H2)
    gemm3_kernel<<<(NN + 127) / 128, 512, 0, stream>>>(x, H, out, V_f32, T2bf);

    // Bucketed CSR build
    zero_counts<<<(NSEG + 255) / 256, 256, 0, stream>>>(counts);
    bucket_hist<<<NBIN, 256, 0, stream>>>(edge_rows, counts);
    scan_segs<<<1, 1024, 0, stream>>>(counts, cursor, bucket_ptr);
    bin_scatter<<<NBIN, 256, 0, stream>>>(edge_rows, edge_cols, edge_vals,
                                          cursor, recs);
    bucket_csr<<<NBUK, 256, 0, stream>>>(recs, bucket_ptr, row_ptr);

    // Vbf = bf16(V_f32 + A@T2bf) ; OUT += A@Vbf
    const int spmm_blocks = (NN * 64 + 255) / 256;   // 25000
    spmm_bf_bf <<<spmm_blocks, 256, 0, stream>>>(row_ptr, recs, T2bf, V_f32, Vbf);
    spmm_bf_f32<<<spmm_blocks, 256, 0, stream>>>(row_ptr, recs, Vbf, out);
}

// Round 6
// 651.463 us; speedup vs baseline: 1.2200x; 1.2200x over previous
//
#include <hip/hip_runtime.h>

#define NN 100000
#define NE 3200000
#define FD 128
#define NBUK 782                 // ceil(NN/128), rows per bucket = 128
#define NSEG (NBUK * 8)          // 6256 (bucket-major, group-minor)
#define NBIN 1024                // binning blocks; NE % NBIN == 0
#define CHUNK (NE / NBIN)        // 3125 edges per binning block
#define MAXB 5120                // LDS stage capacity per bucket

typedef __attribute__((ext_vector_type(8))) short short8;   // 8 bf16 = 4 VGPR
typedef __attribute__((ext_vector_type(4))) float f32x4;

// ---------------- bf16 helpers (manual, RNE) ----------------
__device__ inline unsigned int f2bf_bits(float x) {
    unsigned int u = __float_as_uint(x);
    return (u + 0x7fffu + ((u >> 16) & 1u)) >> 16;
}
__device__ inline float bf_lo(unsigned int u) { return __uint_as_float(u << 16); }
__device__ inline float bf_hi(unsigned int u) { return __uint_as_float(u & 0xffff0000u); }

// ---------------------------------------------------------------------------
// cvt_x: X f32 -> Xbf bf16 (row-major, same layout)
// ---------------------------------------------------------------------------
__global__ __launch_bounds__(256)
void cvt_x(const float* __restrict__ X, unsigned short* __restrict__ Xbf) {
    const int total = NN * FD / 4;              // 3.2M float4 items
    const int stride = gridDim.x * blockDim.x;
    for (int i = blockIdx.x * blockDim.x + threadIdx.x; i < total; i += stride) {
        float4 v = reinterpret_cast<const float4*>(X)[i];
        uint2 o = make_uint2(f2bf_bits(v.x) | (f2bf_bits(v.y) << 16),
                             f2bf_bits(v.z) | (f2bf_bits(v.w) << 16));
        reinterpret_cast<uint2*>(Xbf)[i] = o;
    }
}

// cvt_h: H[k][kk][col] f32 -> HbfT[k][col][kk] bf16 (K-contiguous per col)
__global__ __launch_bounds__(256)
void cvt_h(const float* __restrict__ H, unsigned short* __restrict__ HbfT) {
    int i = blockIdx.x * 256 + threadIdx.x;
    if (i < 3 * FD * FD) {
        int k   = i >> 14;
        int rem = i & 16383;
        int kk  = rem >> 7;
        int col = rem & 127;
        HbfT[k * (FD * FD) + col * FD + kk] = (unsigned short)f2bf_bits(H[i]);
    }
}

// ---------------------------------------------------------------------------
// MFMA triple GEMM: OUT = X@H0 (f32), Vbf = bf16(X@H1), T2bf = bf16(X@H2)
// 256 thr = 4 waves; tile M=128; each wave owns rows 32w..32w+31 (2 m-tiles).
// X tile in LDS (32KB bf16, XOR swizzle (row&7)<<4 -> 2-way-free ds_read_b128).
// B frags from global HbfT (96KB, L2-resident, shared by all 782 blocks).
// A/B both loaded 8-k-contiguous per lane: any consistent (group,elem)->k fill
// gives the exact product (HW pairs A and B slot-for-slot), so the result is
// independent of the undocumented per-lane k-order. C/D layout per m89.
// ---------------------------------------------------------------------------
__global__ __launch_bounds__(256, 4)
void gemm3_mfma(const unsigned short* __restrict__ Xbf,
                const unsigned short* __restrict__ HbfT,
                float* __restrict__ OUT,
                unsigned short* __restrict__ Vbf,
                unsigned short* __restrict__ T2bf) {
    __shared__ __align__(16) unsigned short Xs[128 * 128];   // 32 KB, swizzled
    const int tid  = threadIdx.x;
    const int row0 = blockIdx.x * 128;

    // stage X tile: 2048 16B-chunks, 8 iters x 256 threads
    #pragma unroll
    for (int it = 0; it < 8; ++it) {
        int c    = it * 256 + tid;
        int r    = c >> 4;
        int col8 = (c & 15) * 8;             // bf16 col of this 8-elem chunk
        int gr   = row0 + r;
        uint4 v = make_uint4(0u, 0u, 0u, 0u);
        if (gr < NN)
            v = *reinterpret_cast<const uint4*>(Xbf + (size_t)gr * FD + col8);
        int byte = r * 256 + col8 * 2;
        byte ^= (r & 7) << 4;                // XOR swizzle
        *reinterpret_cast<uint4*>(reinterpret_cast<char*>(Xs) + byte) = v;
    }
    __syncthreads();

    const int lane = tid & 63;
    const int w    = tid >> 6;               // wave id: rows 32w..32w+31
    const int l15  = lane & 15;
    const int g4   = lane >> 4;              // 0..3

    // A-frag byte addrs (row fixed per m; k varies by ks)
    int abyte[2];
    #pragma unroll
    for (int m = 0; m < 2; ++m) {
        int arow = 32 * w + 16 * m + l15;
        abyte[m] = arow * 256 + g4 * 16;     // + ks*64 later
    }
    const int swz0 = (l15 & 7) << 4;         // (arow&7)==（l15&7) since 32w+16m≡0 mod 8

    #pragma unroll
    for (int h = 0; h < 3; ++h) {
        f32x4 acc[2][8];
        #pragma unroll
        for (int m = 0; m < 2; ++m)
            #pragma unroll
            for (int n = 0; n < 8; ++n) acc[m][n] = (f32x4)(0.f);

        const unsigned short* Hb = HbfT + h * (FD * FD) + l15 * FD + g4 * 8;

        #pragma unroll
        for (int ks = 0; ks < 4; ++ks) {
            short8 a0 = *reinterpret_cast<const short8*>(
                reinterpret_cast<const char*>(Xs) + ((abyte[0] + ks * 64) ^ swz0));
            short8 a1 = *reinterpret_cast<const short8*>(
                reinterpret_cast<const char*>(Xs) + ((abyte[1] + ks * 64) ^ swz0));
            #pragma unroll
            for (int n = 0; n < 8; ++n) {
                short8 b = *reinterpret_cast<const short8*>(Hb + n * (16 * FD) + ks * 32);
                acc[0][n] = __builtin_amdgcn_mfma_f32_16x16x32_bf16(a0, b, acc[0][n], 0, 0, 0);
                acc[1][n] = __builtin_amdgcn_mfma_f32_16x16x32_bf16(a1, b, acc[1][n], 0, 0, 0);
            }
        }

        // C write: row = 32w + 16m + g4*4 + r, col = 16n + l15   [m89 layout]
        #pragma unroll
        for (int m = 0; m < 2; ++m) {
            #pragma unroll
            for (int r = 0; r < 4; ++r) {
                int gr = row0 + 32 * w + 16 * m + g4 * 4 + r;
                if (gr < NN) {
                    if (h == 0) {
                        float* dst = OUT + (size_t)gr * FD + l15;
                        #pragma unroll
                        for (int n = 0; n < 8; ++n) dst[16 * n] = acc[m][n][r];
                    } else {
                        unsigned short* dst = (h == 1 ? Vbf : T2bf) + (size_t)gr * FD + l15;
                        #pragma unroll
                        for (int n = 0; n < 8; ++n)
                            dst[16 * n] = (unsigned short)f2bf_bits(acc[m][n][r]);
                    }
                }
            }
        }
    }
}

// ---------------------------------------------------------------------------
// Bucketed CSR build (unchanged from round 4).
// ---------------------------------------------------------------------------
__global__ __launch_bounds__(256)
void zero_counts(int* __restrict__ counts) {
    int i = blockIdx.x * 256 + threadIdx.x;
    if (i < NSEG) counts[i] = 0;
}

__global__ __launch_bounds__(256)
void bucket_hist(const int* __restrict__ rows, int* __restrict__ counts) {
    __shared__ int lh[NBUK];
    for (int i = threadIdx.x; i < NBUK; i += 256) lh[i] = 0;
    __syncthreads();
    const int beg = blockIdx.x * CHUNK, end = beg + CHUNK;
    for (int e = beg + threadIdx.x; e < end; e += 256)
        atomicAdd(&lh[rows[e] >> 7], 1);
    __syncthreads();
    const int g = blockIdx.x & 7;
    for (int b = threadIdx.x; b < NBUK; b += 256)
        if (lh[b]) atomicAdd(&counts[b * 8 + g], lh[b]);
}

__global__ __launch_bounds__(1024)
void scan_segs(const int* __restrict__ counts, int* __restrict__ cursor,
               int* __restrict__ bucket_ptr) {
    __shared__ int s[1024];
    const int tid = threadIdx.x;
    const int per = (NSEG + 1023) / 1024;   // 7
    const int base = tid * per;
    int sum = 0;
    for (int i = 0; i < per; ++i) {
        int idx = base + i;
        if (idx < NSEG) sum += counts[idx];
    }
    s[tid] = sum;
    __syncthreads();
    for (int off = 1; off < 1024; off <<= 1) {
        int t = (tid >= off) ? s[tid - off] : 0;
        __syncthreads();
        s[tid] += t;
        __syncthreads();
    }
    int run = s[tid] - sum;                  // exclusive
    for (int i = 0; i < per; ++i) {
        int idx = base + i;
        if (idx < NSEG) {
            cursor[idx] = run;
            if ((idx & 7) == 0) bucket_ptr[idx >> 3] = run;
            run += counts[idx];
        }
    }
    if (tid == 1023) bucket_ptr[NBUK] = NE;
}

// records: x = (rowlow7 << 17) | col17 ; y = val bits
__global__ __launch_bounds__(256)
void bin_scatter(const int* __restrict__ rows, const int* __restrict__ cols,
                 const float* __restrict__ vals, int* __restrict__ cursor,
                 uint2* __restrict__ recs) {
    const int beg = blockIdx.x * CHUNK, end = beg + CHUNK;
    const int g = blockIdx.x & 7;
    for (int e = beg + threadIdx.x; e < end; e += 256) {
        int r = rows[e];
        int b = r >> 7;
        int pos = atomicAdd(&cursor[b * 8 + g], 1);
        recs[pos] = make_uint2(((unsigned)(r & 127) << 17) | (unsigned)cols[e],
                               __float_as_uint(vals[e]));
    }
}

__global__ __launch_bounds__(256)
void bucket_csr(uint2* __restrict__ recs, const int* __restrict__ bucket_ptr,
                int* __restrict__ row_ptr) {
    __shared__ uint2 stage[MAXB];
    __shared__ int lh[128];
    __shared__ int lsc[128];
    const int b = blockIdx.x, tid = threadIdx.x;
    const int beg = bucket_ptr[b], end = bucket_ptr[b + 1];
    const int n = end - beg;

    if (tid < 128) lh[tid] = 0;
    __syncthreads();
    for (int i = tid; i < n; i += 256) {
        uint2 r = recs[beg + i];
        stage[i] = r;
        atomicAdd(&lh[r.x >> 17], 1);
    }
    __syncthreads();
    int v = (tid < 128) ? lh[tid] : 0;
    if (tid < 128) lsc[tid] = v;
    __syncthreads();
    for (int off = 1; off < 128; off <<= 1) {
        int t = 0;
        if (tid < 128 && tid >= off) t = lsc[tid - off];
        __syncthreads();
        if (tid < 128) lsc[tid] += t;
        __syncthreads();
    }
    if (tid < 128) {
        int excl = lsc[tid] - v;
        int gr = b * 128 + tid;
        if (gr <= NN) row_ptr[gr] = beg + excl;
        lh[tid] = excl;                            // reuse as local cursor
    }
    __syncthreads();
    for (int i = tid; i < n; i += 256) {
        uint2 r = stage[i];
        int pos = atomicAdd(&lh[r.x >> 17], 1);
        recs[beg + pos] = r;
    }
}

// ---------------------------------------------------------------------------
// SpMM (CSR, bf16 gathers, fp32 accumulate). One wave per dest row; lane =
// (edge-parity l>>5, feature-quad l&31); 512B per gather instruction.
// ---------------------------------------------------------------------------
#define SPMM_BODY(STORE)                                                       \
    const int lane = threadIdx.x & 63;                                         \
    const int row  = (blockIdx.x * blockDim.x + threadIdx.x) >> 6;             \
    if (row >= NN) return;                                                     \
    const int sub = lane >> 5;      /* which edge of the pair */               \
    const int fq  = lane & 31;      /* feature quad: fq*4..fq*4+3 */           \
    const int beg = row_ptr[row], end = row_ptr[row + 1];                      \
    float4 acc = make_float4(0.f, 0.f, 0.f, 0.f);                              \
    int e = beg + sub;                                                         \
    for (; e + 14 < end; e += 16) {                                            \
        uint2 p[8];                                                            \
        uint2 g[8];                                                            \
        _Pragma("unroll")                                                      \
        for (int u = 0; u < 8; ++u) p[u] = recs[e + 2 * u];                    \
        _Pragma("unroll")                                                      \
        for (int u = 0; u < 8; ++u)                                            \
            g[u] = *reinterpret_cast<const uint2*>(                            \
                src + (size_t)(p[u].x & 0x1FFFF) * FD + fq * 4);               \
        _Pragma("unroll")                                                      \
        for (int u = 0; u < 8; ++u) {                                          \
            float v = __uint_as_float(p[u].y);                                 \
            acc.x += v * bf_lo(g[u].x); acc.y += v * bf_hi(g[u].x);            \
            acc.z += v * bf_lo(g[u].y); acc.w += v * bf_hi(g[u].y);            \
        }                                                                      \
    }                                                                          \
    for (; e < end; e += 2) {                                                  \
        uint2 p = recs[e];                                                     \
        uint2 g = *reinterpret_cast<const uint2*>(                             \
            src + (size_t)(p.x & 0x1FFFF) * FD + fq * 4);                      \
        float v = __uint_as_float(p.y);                                        \
        acc.x += v * bf_lo(g.x); acc.y += v * bf_hi(g.x);                      \
        acc.z += v * bf_lo(g.y); acc.w += v * bf_hi(g.y);                      \
    }                                                                          \
    acc.x += __shfl_xor(acc.x, 32, 64);                                        \
    acc.y += __shfl_xor(acc.y, 32, 64);                                        \
    acc.z += __shfl_xor(acc.z, 32, 64);                                        \
    acc.w += __shfl_xor(acc.w, 32, 64);                                        \
    if (sub == 0) { STORE }

// spmm1: Vbf = bf16( Vbf_init + A @ T2bf )   (in-place on Vbf, per-row safe)
__global__ __launch_bounds__(256)
void spmm_bf_bf(const int* __restrict__ row_ptr, const uint2* __restrict__ recs,
                const unsigned short* __restrict__ src,
                unsigned short* __restrict__ initdst) {
    SPMM_BODY({
        uint2 iv = *reinterpret_cast<const uint2*>(initdst + (size_t)row * FD + fq * 4);
        acc.x += bf_lo(iv.x); acc.y += bf_hi(iv.x);
        acc.z += bf_lo(iv.y); acc.w += bf_hi(iv.y);
        unsigned int w0 = f2bf_bits(acc.x) | (f2bf_bits(acc.y) << 16);
        unsigned int w1 = f2bf_bits(acc.z) | (f2bf_bits(acc.w) << 16);
        *reinterpret_cast<uint2*>(initdst + (size_t)row * FD + fq * 4) = make_uint2(w0, w1);
    })
}

// spmm2: OUT += A @ Vbf   (f32 accumulate into existing OUT)
__global__ __launch_bounds__(256)
void spmm_bf_f32(const int* __restrict__ row_ptr, const uint2* __restrict__ recs,
                 const unsigned short* __restrict__ src, float* __restrict__ dst) {
    SPMM_BODY({
        float4 iv = *reinterpret_cast<const float4*>(dst + (size_t)row * FD + fq * 4);
        acc.x += iv.x; acc.y += iv.y; acc.z += iv.z; acc.w += iv.w;
        *reinterpret_cast<float4*>(dst + (size_t)row * FD + fq * 4) = acc;
    })
}

extern "C" void kernel_launch(void* const* d_in, const int* in_sizes, int n_in,
                              void* d_out, int out_size, void* d_ws, size_t ws_size,
                              hipStream_t stream) {
    const int*   edge_rows = (const int*)d_in[0];
    const int*   edge_cols = (const int*)d_in[1];
    const float* edge_vals = (const float*)d_in[2];
    const float* x         = (const float*)d_in[3];
    const float* H         = (const float*)d_in[4];
    float*       out       = (float*)d_out;

    // workspace layout (~103 MB total)
    const size_t feat = (size_t)NN * FD;
    unsigned short* Xbf  = (unsigned short*)d_ws;              // 25.6 MB
    unsigned short* T2bf = Xbf + feat;                         // 25.6 MB
    unsigned short* Vbf  = T2bf + feat;                        // 25.6 MB
    unsigned short* HbfT = Vbf + feat;                         // 96 KB
    uint2*          recs = (uint2*)(HbfT + 3 * FD * FD);       // 25.6 MB
    int* counts     = (int*)(recs + NE);
    int* cursor     = counts + NSEG;
    int* row_ptr    = cursor + NSEG;
    int* bucket_ptr = row_ptr + NN + 1;

    // bf16 conversions
    cvt_x<<<2048, 256, 0, stream>>>(x, Xbf);
    cvt_h<<<(3 * FD * FD + 255) / 256, 256, 0, stream>>>(H, HbfT);

    // OUT = X@H0, Vbf = bf16(X@H1), T2bf = bf16(X@H2)
    gemm3_mfma<<<(NN + 127) / 128, 256, 0, stream>>>(Xbf, HbfT, out, Vbf, T2bf);

    // Bucketed CSR build
    zero_counts<<<(NSEG + 255) / 256, 256, 0, stream>>>(counts);
    bucket_hist<<<NBIN, 256, 0, stream>>>(edge_rows, counts);
    scan_segs<<<1, 1024, 0, stream>>>(counts, cursor, bucket_ptr);
    bin_scatter<<<NBIN, 256, 0, stream>>>(edge_rows, edge_cols, edge_vals,
                                          cursor, recs);
    bucket_csr<<<NBUK, 256, 0, stream>>>(recs, bucket_ptr, row_ptr);

    // Vbf = bf16(Vbf + A@T2bf) ; OUT += A@Vbf
    const int spmm_blocks = (NN * 64 + 255) / 256;   // 25000
    spmm_bf_bf <<<spmm_blocks, 256, 0, stream>>>(row_ptr, recs, T2bf, Vbf);
    spmm_bf_f32<<<spmm_blocks, 256, 0, stream>>>(row_ptr, recs, Vbf, out);
}

// Round 7
// 555.485 us; speedup vs baseline: 1.4307x; 1.1728x over previous
//
#include <hip/hip_runtime.h>

#define NN 100000
#define NE 3200000
#define FD 128
#define PROWS 256                // rows per partition (p = row >> 8)
#define NPART 391                // ceil(NN / PROWS)
#define PBIN 512                 // partition-pass blocks; NE % PBIN == 0
#define PCHUNK (NE / PBIN)       // 6250 edges per block

typedef __attribute__((ext_vector_type(8))) short short8;   // 8 bf16 = 4 VGPR
typedef __attribute__((ext_vector_type(4))) float f32x4;

// ---------------- bf16 helpers (manual, RNE) ----------------
__device__ inline unsigned int f2bf_bits(float x) {
    unsigned int u = __float_as_uint(x);
    return (u + 0x7fffu + ((u >> 16) & 1u)) >> 16;
}
__device__ inline float bf_lo(unsigned int u) { return __uint_as_float(u << 16); }
__device__ inline float bf_hi(unsigned int u) { return __uint_as_float(u & 0xffff0000u); }

// cvt_h: H[k][kk][col] f32 -> HbfT[k][col][kk] bf16 (K-contiguous per col)
__global__ __launch_bounds__(256)
void cvt_h(const float* __restrict__ H, unsigned short* __restrict__ HbfT) {
    int i = blockIdx.x * 256 + threadIdx.x;
    if (i < 3 * FD * FD) {
        int k   = i >> 14;
        int rem = i & 16383;
        int kk  = rem >> 7;
        int col = rem & 127;
        HbfT[k * (FD * FD) + col * FD + kk] = (unsigned short)f2bf_bits(H[i]);
    }
}

// ---------------------------------------------------------------------------
// MFMA triple GEMM: OUT = X@H0 (f32), Vbf = bf16(X@H1), T2bf = bf16(X@H2)
// X read as f32 and converted to bf16 during the LDS stage (no cvt_x pass).
// 4 waves; wave owns rows 32w..32w+31. Xs XOR-swizzled (row&7)<<4.
// ---------------------------------------------------------------------------
__global__ __launch_bounds__(256, 4)
void gemm3_mfma(const float* __restrict__ X,
                const unsigned short* __restrict__ HbfT,
                float* __restrict__ OUT,
                unsigned short* __restrict__ Vbf,
                unsigned short* __restrict__ T2bf) {
    __shared__ __align__(16) unsigned short Xs[128 * 128];   // 32 KB, swizzled
    const int tid  = threadIdx.x;
    const int row0 = blockIdx.x * 128;

    #pragma unroll
    for (int it = 0; it < 8; ++it) {
        int c    = it * 256 + tid;
        int r    = c >> 4;
        int col8 = (c & 15) * 8;             // bf16 col of this 8-elem chunk
        int gr   = row0 + r;
        uint4 v = make_uint4(0u, 0u, 0u, 0u);
        if (gr < NN) {
            float4 a = *reinterpret_cast<const float4*>(X + (size_t)gr * FD + col8);
            float4 b = *reinterpret_cast<const float4*>(X + (size_t)gr * FD + col8 + 4);
            v.x = f2bf_bits(a.x) | (f2bf_bits(a.y) << 16);
            v.y = f2bf_bits(a.z) | (f2bf_bits(a.w) << 16);
            v.z = f2bf_bits(b.x) | (f2bf_bits(b.y) << 16);
            v.w = f2bf_bits(b.z) | (f2bf_bits(b.w) << 16);
        }
        int byte = r * 256 + col8 * 2;
        byte ^= (r & 7) << 4;                // XOR swizzle
        *reinterpret_cast<uint4*>(reinterpret_cast<char*>(Xs) + byte) = v;
    }
    __syncthreads();

    const int lane = tid & 63;
    const int w    = tid >> 6;               // wave id: rows 32w..32w+31
    const int l15  = lane & 15;
    const int g4   = lane >> 4;              // 0..3

    int abyte[2];
    #pragma unroll
    for (int m = 0; m < 2; ++m) {
        int arow = 32 * w + 16 * m + l15;
        abyte[m] = arow * 256 + g4 * 16;     // + ks*64 later
    }
    const int swz0 = (l15 & 7) << 4;

    #pragma unroll
    for (int h = 0; h < 3; ++h) {
        f32x4 acc[2][8];
        #pragma unroll
        for (int m = 0; m < 2; ++m)
            #pragma unroll
            for (int n = 0; n < 8; ++n) acc[m][n] = (f32x4)(0.f);

        const unsigned short* Hb = HbfT + h * (FD * FD) + l15 * FD + g4 * 8;

        #pragma unroll
        for (int ks = 0; ks < 4; ++ks) {
            short8 a0 = *reinterpret_cast<const short8*>(
                reinterpret_cast<const char*>(Xs) + ((abyte[0] + ks * 64) ^ swz0));
            short8 a1 = *reinterpret_cast<const short8*>(
                reinterpret_cast<const char*>(Xs) + ((abyte[1] + ks * 64) ^ swz0));
            #pragma unroll
            for (int n = 0; n < 8; ++n) {
                short8 b = *reinterpret_cast<const short8*>(Hb + n * (16 * FD) + ks * 32);
                acc[0][n] = __builtin_amdgcn_mfma_f32_16x16x32_bf16(a0, b, acc[0][n], 0, 0, 0);
                acc[1][n] = __builtin_amdgcn_mfma_f32_16x16x32_bf16(a1, b, acc[1][n], 0, 0, 0);
            }
        }

        // C write: row = 32w + 16m + g4*4 + r, col = 16n + l15   [m89 layout]
        #pragma unroll
        for (int m = 0; m < 2; ++m) {
            #pragma unroll
            for (int r = 0; r < 4; ++r) {
                int gr = row0 + 32 * w + 16 * m + g4 * 4 + r;
                if (gr < NN) {
                    if (h == 0) {
                        float* dst = OUT + (size_t)gr * FD + l15;
                        #pragma unroll
                        for (int n = 0; n < 8; ++n) dst[16 * n] = acc[m][n][r];
                    } else {
                        unsigned short* dst = (h == 1 ? Vbf : T2bf) + (size_t)gr * FD + l15;
                        #pragma unroll
                        for (int n = 0; n < 8; ++n)
                            dst[16 * n] = (unsigned short)f2bf_bits(acc[m][n][r]);
                    }
                }
            }
        }
    }
}

// ---------------------------------------------------------------------------
// Partition-sort CSR build. All global writes are into block-private
// contiguous ranges -> full-cacheline writebacks regardless of XCD mapping.
// record: x = (rowlocal8 << 17) | col17 ; y = val bits
// ---------------------------------------------------------------------------
__global__ __launch_bounds__(512)
void zero_small(int* __restrict__ p, int n) {
    int i = blockIdx.x * 512 + threadIdx.x;
    if (i < n) p[i] = 0;
}

__global__ __launch_bounds__(256)
void phist(const int* __restrict__ rows, int* __restrict__ pcount) {
    __shared__ int lh[NPART];
    for (int i = threadIdx.x; i < NPART; i += 256) lh[i] = 0;
    __syncthreads();
    const int beg = blockIdx.x * PCHUNK, end = beg + PCHUNK;
    for (int e = beg + threadIdx.x; e < end; e += 256)
        atomicAdd(&lh[rows[e] >> 8], 1);
    __syncthreads();
    for (int i = threadIdx.x; i < NPART; i += 256)
        if (lh[i]) atomicAdd(&pcount[i], lh[i]);
}

__global__ __launch_bounds__(512)
void pscan(const int* __restrict__ pcount, int* __restrict__ pbase,
           int* __restrict__ pcursor) {
    __shared__ int s[512];
    const int tid = threadIdx.x;
    int v = (tid < NPART) ? pcount[tid] : 0;
    s[tid] = v;
    __syncthreads();
    for (int off = 1; off < 512; off <<= 1) {
        int t = (tid >= off) ? s[tid - off] : 0;
        __syncthreads();
        s[tid] += t;
        __syncthreads();
    }
    int excl = s[tid] - v;
    if (tid < NPART) { pbase[tid] = excl; pcursor[tid] = excl; }
    if (tid == 0) pbase[NPART] = NE;
}

__global__ __launch_bounds__(256)
void part_scatter(const int* __restrict__ rows, const int* __restrict__ cols,
                  const float* __restrict__ vals, int* __restrict__ pcursor,
                  uint2* __restrict__ recs) {
    __shared__ int lh[NPART];
    __shared__ int lcur[NPART];
    for (int i = threadIdx.x; i < NPART; i += 256) lh[i] = 0;
    __syncthreads();
    const int beg = blockIdx.x * PCHUNK, end = beg + PCHUNK;
    for (int e = beg + threadIdx.x; e < end; e += 256)
        atomicAdd(&lh[rows[e] >> 8], 1);
    __syncthreads();
    // reserve a PRIVATE contiguous range per (block, partition)
    for (int i = threadIdx.x; i < NPART; i += 256)
        lcur[i] = lh[i] ? atomicAdd(&pcursor[i], lh[i]) : 0;
    __syncthreads();
    for (int e = beg + threadIdx.x; e < end; e += 256) {
        int r = rows[e];
        int p = r >> 8;
        int pos = atomicAdd(&lcur[p], 1);
        recs[pos] = make_uint2(((unsigned)(r & 255) << 17) | (unsigned)cols[e],
                               __float_as_uint(vals[e]));
    }
}

// One block per partition: 256-bin row hist + scan, scatter recs->recs2
// row-sorted (writes confined to this block's ~64KB L2-resident region),
// emit row_ptr. For the last partition, beg+excl naturally yields row_ptr[NN]=NE.
__global__ __launch_bounds__(256)
void row_sort(const uint2* __restrict__ recs, const int* __restrict__ pbase,
              uint2* __restrict__ recs2, int* __restrict__ row_ptr) {
    __shared__ int rh[256];
    __shared__ int rsc[256];
    __shared__ int rcur[256];
    const int p = blockIdx.x, tid = threadIdx.x;
    const int beg = pbase[p], end = pbase[p + 1];

    rh[tid] = 0;
    __syncthreads();
    for (int i = beg + tid; i < end; i += 256)
        atomicAdd(&rh[recs[i].x >> 17], 1);
    __syncthreads();
    int v = rh[tid];
    rsc[tid] = v;
    __syncthreads();
    for (int off = 1; off < 256; off <<= 1) {
        int t = (tid >= off) ? rsc[tid - off] : 0;
        __syncthreads();
        rsc[tid] += t;
        __syncthreads();
    }
    int excl = rsc[tid] - v;
    int gr = p * PROWS + tid;
    if (gr <= NN) row_ptr[gr] = beg + excl;
    rcur[tid] = beg + excl;
    __syncthreads();
    for (int i = beg + tid; i < end; i += 256) {
        uint2 u = recs[i];
        int pos = atomicAdd(&rcur[u.x >> 17], 1);
        recs2[pos] = u;
    }
}

// ---------------------------------------------------------------------------
// SpMM (CSR, bf16 gathers, fp32 accumulate). One wave per dest row; lane =
// (edge-parity l>>5, feature-quad l&31); 512B per gather instruction.
// ---------------------------------------------------------------------------
#define SPMM_BODY(STORE)                                                       \
    const int lane = threadIdx.x & 63;                                         \
    const int row  = (blockIdx.x * blockDim.x + threadIdx.x) >> 6;             \
    if (row >= NN) return;                                                     \
    const int sub = lane >> 5;      /* which edge of the pair */               \
    const int fq  = lane & 31;      /* feature quad: fq*4..fq*4+3 */           \
    const int beg = row_ptr[row], end = row_ptr[row + 1];                      \
    float4 acc = make_float4(0.f, 0.f, 0.f, 0.f);                              \
    int e = beg + sub;                                                         \
    for (; e + 14 < end; e += 16) {                                            \
        uint2 p[8];                                                            \
        uint2 g[8];                                                            \
        _Pragma("unroll")                                                      \
        for (int u = 0; u < 8; ++u) p[u] = recs[e + 2 * u];                    \
        _Pragma("unroll")                                                      \
        for (int u = 0; u < 8; ++u)                                            \
            g[u] = *reinterpret_cast<const uint2*>(                            \
                src + (size_t)(p[u].x & 0x1FFFF) * FD + fq * 4);               \
        _Pragma("unroll")                                                      \
        for (int u = 0; u < 8; ++u) {                                          \
            float v = __uint_as_float(p[u].y);                                 \
            acc.x += v * bf_lo(g[u].x); acc.y += v * bf_hi(g[u].x);            \
            acc.z += v * bf_lo(g[u].y); acc.w += v * bf_hi(g[u].y);            \
        }                                                                      \
    }                                                                          \
    for (; e < end; e += 2) {                                                  \
        uint2 p = recs[e];                                                     \
        uint2 g = *reinterpret_cast<const uint2*>(                             \
            src + (size_t)(p.x & 0x1FFFF) * FD + fq * 4);                      \
        float v = __uint_as_float(p.y);                                        \
        acc.x += v * bf_lo(g.x); acc.y += v * bf_hi(g.x);                      \
        acc.z += v * bf_lo(g.y); acc.w += v * bf_hi(g.y);                      \
    }                                                                          \
    acc.x += __shfl_xor(acc.x, 32, 64);                                        \
    acc.y += __shfl_xor(acc.y, 32, 64);                                        \
    acc.z += __shfl_xor(acc.z, 32, 64);                                        \
    acc.w += __shfl_xor(acc.w, 32, 64);                                        \
    if (sub == 0) { STORE }

// spmm1: Vbf = bf16( Vbf_init + A @ T2bf )   (in-place on Vbf, per-row safe)
__global__ __launch_bounds__(256)
void spmm_bf_bf(const int* __restrict__ row_ptr, const uint2* __restrict__ recs,
                const unsigned short* __restrict__ src,
                unsigned short* __restrict__ initdst) {
    SPMM_BODY({
        uint2 iv = *reinterpret_cast<const uint2*>(initdst + (size_t)row * FD + fq * 4);
        acc.x += bf_lo(iv.x); acc.y += bf_hi(iv.x);
        acc.z += bf_lo(iv.y); acc.w += bf_hi(iv.y);
        unsigned int w0 = f2bf_bits(acc.x) | (f2bf_bits(acc.y) << 16);
        unsigned int w1 = f2bf_bits(acc.z) | (f2bf_bits(acc.w) << 16);
        *reinterpret_cast<uint2*>(initdst + (size_t)row * FD + fq * 4) = make_uint2(w0, w1);
    })
}

// spmm2: OUT += A @ Vbf   (f32 accumulate into existing OUT)
__global__ __launch_bounds__(256)
void spmm_bf_f32(const int* __restrict__ row_ptr, const uint2* __restrict__ recs,
                 const unsigned short* __restrict__ src, float* __restrict__ dst) {
    SPMM_BODY({
        float4 iv = *reinterpret_cast<const float4*>(dst + (size_t)row * FD + fq * 4);
        acc.x += iv.x; acc.y += iv.y; acc.z += iv.z; acc.w += iv.w;
        *reinterpret_cast<float4*>(dst + (size_t)row * FD + fq * 4) = acc;
    })
}

extern "C" void kernel_launch(void* const* d_in, const int* in_sizes, int n_in,
                              void* d_out, int out_size, void* d_ws, size_t ws_size,
                              hipStream_t stream) {
    const int*   edge_rows = (const int*)d_in[0];
    const int*   edge_cols = (const int*)d_in[1];
    const float* edge_vals = (const float*)d_in[2];
    const float* x         = (const float*)d_in[3];
    const float* H         = (const float*)d_in[4];
    float*       out       = (float*)d_out;

    // workspace layout (~103 MB total)
    const size_t feat = (size_t)NN * FD;
    unsigned short* T2bf = (unsigned short*)d_ws;              // 25.6 MB
    unsigned short* Vbf  = T2bf + feat;                        // 25.6 MB
    unsigned short* HbfT = Vbf + feat;                         // 96 KB
    uint2*          recs = (uint2*)(HbfT + 3 * FD * FD);       // 25.6 MB
    uint2*          recs2 = recs + NE;                         // 25.6 MB
    int* pcount  = (int*)(recs2 + NE);                         // 1.6 KB
    int* pbase   = pcount + NPART;                             // 1.6 KB
    int* pcursor = pbase + NPART + 1;                          // 1.6 KB
    int* row_ptr = pcursor + NPART;                            // 400 KB

    // H -> bf16 transposed; triple GEMM (converts X to bf16 in its LDS stage)
    cvt_h<<<(3 * FD * FD + 255) / 256, 256, 0, stream>>>(H, HbfT);
    gemm3_mfma<<<(NN + 127) / 128, 256, 0, stream>>>(x, HbfT, out, Vbf, T2bf);

    // Partition-sort CSR build
    zero_small<<<1, 512, 0, stream>>>(pcount, NPART);
    phist<<<PBIN, 256, 0, stream>>>(edge_rows, pcount);
    pscan<<<1, 512, 0, stream>>>(pcount, pbase, pcursor);
    part_scatter<<<PBIN, 256, 0, stream>>>(edge_rows, edge_cols, edge_vals,
                                           pcursor, recs);
    row_sort<<<NPART, 256, 0, stream>>>(recs, pbase, recs2, row_ptr);

    // Vbf = bf16(Vbf + A@T2bf) ; OUT += A@Vbf
    const int spmm_blocks = (NN * 64 + 255) / 256;   // 25000
    spmm_bf_bf <<<spmm_blocks, 256, 0, stream>>>(row_ptr, recs2, T2bf, Vbf);
    spmm_bf_f32<<<spmm_blocks, 256, 0, stream>>>(row_ptr, recs2, Vbf, out);
}